// Round 9
// baseline (290.532 us; speedup 1.0000x reference)
//
#include <hip/hip_runtime.h>
#include <hip/hip_bf16.h>
#include <cstdint>

// Problem constants (fixed by setup_inputs)
#define B_  2
#define S_  2048
#define D_  1024
#define H_  16
#define DK_ 64

typedef unsigned short u16;
typedef __attribute__((ext_vector_type(8))) __bf16 bf16x8;
typedef __attribute__((ext_vector_type(4))) float  f32x4;

__device__ __forceinline__ u16 f2bf(float f) {
  union { float f; uint32_t u; } x; x.f = f;
  uint32_t r = (x.u + 0x7fffu + ((x.u >> 16) & 1u)) >> 16;  // RNE
  return (u16)r;
}

// v_cvt_pk_bf16_f32: D.lo = bf16(lo), D.hi = bf16(hi). No builtin on gfx950 (m240).
__device__ __forceinline__ uint32_t cvt_pk_bf16(float lo, float hi) {
  uint32_t r;
  asm volatile("v_cvt_pk_bf16_f32 %0, %1, %2" : "=v"(r) : "v"(lo), "v"(hi));
  return r;
}

__device__ __forceinline__ void gload_lds16(const void* g, void* l) {
  __builtin_amdgcn_global_load_lds(
      (const __attribute__((address_space(1))) void*)g,
      (__attribute__((address_space(3))) void*)l, 16, 0, 0);
}

// ---------------- RoPE tables (fp64 for accuracy) ----------------
__global__ __launch_bounds__(256) void rope_tables_k(float* __restrict__ cosT,
                                                     float* __restrict__ sinT) {
  int idx = blockIdx.x * 256 + threadIdx.x;   // S_*512 entries
  int s = idx >> 9;
  int i = idx & 511;
  double theta = exp((-2.0 * (double)i / (double)D_) * log(10000.0));
  double arg = (double)(s + 1) * theta;       // positions start at 1
  cosT[idx] = (float)cos(arg);
  sinT[idx] = (float)sin(arg);
}

// ---------------- RoPE apply on q,k + bf16 convert v ----------------
__global__ __launch_bounds__(256) void rope_apply(
    const float* __restrict__ q, const float* __restrict__ k, const float* __restrict__ v,
    const float* __restrict__ cosT, const float* __restrict__ sinT,
    u16* __restrict__ qr, u16* __restrict__ kr, u16* __restrict__ vb) {
  const int row = blockIdx.x;        // 0..B_*S_-1
  const int j   = threadIdx.x;       // 0..255 (pair index)
  const int s   = row & (S_ - 1);
  const float c0 = cosT[s * 512 + j],       s0 = sinT[s * 512 + j];
  const float c1 = cosT[s * 512 + 256 + j], s1 = sinT[s * 512 + 256 + j];
  const size_t off = (size_t)row * D_;

  float2 qa = *(const float2*)(q + off + 2 * j);
  float2 qb = *(const float2*)(q + off + 2 * j + 512);
  qr[off + 2*j]       = f2bf(qa.x * c0 - qb.x * s0);
  qr[off + 2*j + 1]   = f2bf(qa.y * c0 - qb.y * s0);
  qr[off + 2*j + 512] = f2bf(qb.x * c1 + qa.x * s1);
  qr[off + 2*j + 513] = f2bf(qb.y * c1 + qa.y * s1);

  float2 ka = *(const float2*)(k + off + 2 * j);
  float2 kb = *(const float2*)(k + off + 2 * j + 512);
  kr[off + 2*j]       = f2bf(ka.x * c0 - kb.x * s0);
  kr[off + 2*j + 1]   = f2bf(ka.y * c0 - kb.y * s0);
  kr[off + 2*j + 512] = f2bf(kb.x * c1 + ka.x * s1);
  kr[off + 2*j + 513] = f2bf(kb.y * c1 + ka.y * s1);

  float2 va = *(const float2*)(v + off + 2 * j);
  float2 vv = *(const float2*)(v + off + 2 * j + 512);
  vb[off + 2*j]       = f2bf(va.x);
  vb[off + 2*j + 1]   = f2bf(va.y);
  vb[off + 2*j + 512] = f2bf(vv.x);
  vb[off + 2*j + 513] = f2bf(vv.y);
}

// ---------------- weight fp32 -> bf16 (all four in one launch) ----------------
__global__ __launch_bounds__(256) void cvt4_k(const float* __restrict__ w0,
                                              const float* __restrict__ w1,
                                              const float* __restrict__ w2,
                                              const float* __restrict__ w3,
                                              u16* __restrict__ out) {
  int i = (blockIdx.x * 256 + threadIdx.x) * 4;   // 4*D_*D_ elements total
  int which = i >> 20;                            // 1M elements per matrix
  const float* src = which == 0 ? w0 : which == 1 ? w1 : which == 2 ? w2 : w3;
  float4 f = *(const float4*)(src + (i & 1048575));
  out[i]     = f2bf(f.x);
  out[i + 1] = f2bf(f.y);
  out[i + 2] = f2bf(f.z);
  out[i + 3] = f2bf(f.w);
}

// ---------------- GEMM: C = A(M,K) * W(N,K)^T + bias ----------------
// 128x64 tile, BK=32, 2-phase dbuf staging, 1 barrier/step. LDS 24 KB ->
// grid 512 = 2 blocks/CU = 2 waves/SIMD. Chunk swizzle: source chunk
// (c&3)^((row>>1)&3); read chunk g^((r>>1)&3) -> retrieves source chunk g
// (XOR involution cancels). XCD-chunked blockIdx.
// mode 0: bf16 out -> (B,H,S,DK); mode 1: bf16 -> (B,H,DK,S);
// mode 2: fp32 out row-major.
__global__ __launch_bounds__(256) void gemm_bt2(
    const u16* __restrict__ A, const u16* __restrict__ W,
    const float* __restrict__ bias, void* __restrict__ out,
    int M, int N, int K, int mode) {
  __shared__ __align__(16) u16 At[2][128 * 32];
  __shared__ __align__(16) u16 Bt[2][64 * 32];
  const int tid  = threadIdx.x;
  const int lane = tid & 63;
  const int wv   = tid >> 6;
  const int wm   = wv >> 1, wn = wv & 1;   // wave tile 64x32
  // XCD chunking: 512 blocks, 64 consecutive per XCD (same tileM rows share A)
  const int sw = (blockIdx.x & 7) * 64 + (blockIdx.x >> 3);
  const int tileM = (sw >> 4) * 128;
  const int tileN = (sw & 15) * 64;
  const int lr = lane & 15;
  const int g  = lane >> 4;

  f32x4 acc[4][2];
#pragma unroll
  for (int i = 0; i < 4; ++i)
#pragma unroll
    for (int j = 0; j < 2; ++j) acc[i][j] = (f32x4){0.f, 0.f, 0.f, 0.f};

  // Stage A 128x32 (512 chunks, 2/thread) + B 64x32 (256 chunks, 1/thread).
  // LDS dest wave-uniform base (+ lane*16 implicit); source chunk pre-swizzled.
#define GSTAGE(buf, kbn) do {                                                  \
    _Pragma("unroll")                                                          \
    for (int r2 = 0; r2 < 2; ++r2) {                                           \
      int c = r2 * 256 + tid;                                                  \
      int row = c >> 2;                                                        \
      int sch = ((c & 3) ^ ((row >> 1) & 3)) * 8;                              \
      gload_lds16(A + (size_t)(tileM + row) * K + (kbn) + sch,                 \
                  (void*)(At[buf] + (r2 * 256 + wv * 64) * 8));                \
    }                                                                          \
    {                                                                          \
      int c = tid;                                                             \
      int row = c >> 2;                                                        \
      int sch = ((c & 3) ^ ((row >> 1) & 3)) * 8;                              \
      gload_lds16(W + (size_t)(tileN + row) * K + (kbn) + sch,                 \
                  (void*)(Bt[buf] + (wv * 64) * 8));                           \
    }                                                                          \
  } while (0)

  GSTAGE(0, 0);
  __syncthreads();
  for (int kb = 0; kb < K; kb += 32) {
    const int cur = (kb >> 5) & 1;
    if (kb + 32 < K) GSTAGE(cur ^ 1, kb + 32);
    bf16x8 af[4], bfr[2];
#pragma unroll
    for (int i = 0; i < 4; ++i) {
      int r = wm * 64 + i * 16 + lr;
      af[i] = *(const bf16x8*)(At[cur] + r * 32 + (g ^ ((r >> 1) & 3)) * 8);
    }
#pragma unroll
    for (int i = 0; i < 2; ++i) {
      int r = wn * 32 + i * 16 + lr;
      bfr[i] = *(const bf16x8*)(Bt[cur] + r * 32 + (g ^ ((r >> 1) & 3)) * 8);
    }
#pragma unroll
    for (int mi = 0; mi < 4; ++mi)
#pragma unroll
      for (int ni = 0; ni < 2; ++ni)
        acc[mi][ni] = __builtin_amdgcn_mfma_f32_16x16x32_bf16(af[mi], bfr[ni],
                                                              acc[mi][ni], 0, 0, 0);
    __syncthreads();   // drains staging vmcnt; all waves done reading cur
  }
#undef GSTAGE

  // Epilogue. D-layout (m89-verified): col = lane&15, row = (lane>>4)*4 + reg
#pragma unroll
  for (int mi = 0; mi < 4; ++mi)
#pragma unroll
    for (int ni = 0; ni < 2; ++ni)
#pragma unroll
      for (int r = 0; r < 4; ++r) {
        int m = tileM + wm * 64 + mi * 16 + g * 4 + r;
        int n = tileN + wn * 32 + ni * 16 + lr;
        float val = acc[mi][ni][r] + bias[n];
        if (mode == 2) {
          ((float*)out)[(size_t)m * N + n] = val;
        } else {
          int bb = m >> 11, ss = m & (S_ - 1);
          int hh = n >> 6, dk = n & 63;
          if (mode == 0)
            ((u16*)out)[(((size_t)(bb * H_ + hh) * S_ + ss) << 6) + dk] = f2bf(val);
          else
            ((u16*)out)[(((size_t)(bb * H_ + hh) * DK_ + dk) << 11) + ss] = f2bf(val);
        }
      }
}

// ---------------- flash attention v5 (round-7 proven, verbatim) ----------------
// Swapped QK^T, fixed-shift softmax, per-wave P staging, XCD swizzle,
// K-tile LDS dbuf staging (1 barrier/tile), V early reg loads.
__global__ __launch_bounds__(256, 2) void attn_kernel(
    const u16* __restrict__ Qh, const u16* __restrict__ Kh,
    const u16* __restrict__ Vt, u16* __restrict__ Oout) {
  __shared__ __align__(16) u16 Kt[2][64 * 64];     // [buf][row][64 u16] 8KB each
  __shared__ __align__(16) u16 Plds[4][32 * 72];   // per-wave P staging
  const int lane = threadIdx.x & 63;
  const int wv   = threadIdx.x >> 6;
  const int lr = lane & 15, g = lane >> 4, lk = g * 8;
  const int swzm = (lr & 3) << 4;                  // P-staging col XOR mask
  // XCD swizzle: 512 blocks; bid%8 = XCD, chunks of 64 -> 4 heads per XCD.
  const int sw = (blockIdx.x & 7) * 64 + (blockIdx.x >> 3);
  const int bh = sw >> 4;                          // 0..31
  const int qb = (sw & 15) * 128;
  const int b = bh >> 4, h = bh & 15;
  const size_t base = (size_t)bh * S_ * DK_;
  const int qrow = qb + wv * 32;
  u16* Pw = &Plds[wv][0];

  // Q fragments (B-operand of swapped QK): Q[(qrow+m*16+lr)][i*32+lk..+7]
  bf16x8 qf[2][2];
#pragma unroll
  for (int m = 0; m < 2; ++m)
#pragma unroll
    for (int i = 0; i < 2; ++i)
      qf[m][i] = *(const bf16x8*)(Qh + base + (size_t)(qrow + m * 16 + lr) * DK_ + i * 32 + lk);

  f32x4 acc[2][4];
  f32x4 lsum[2];
#pragma unroll
  for (int m = 0; m < 2; ++m) {
    lsum[m] = (f32x4){0.f, 0.f, 0.f, 0.f};
#pragma unroll
    for (int n = 0; n < 4; ++n) acc[m][n] = (f32x4){0.f, 0.f, 0.f, 0.f};
  }

  const float C1 = 0.18033688f;   // (1/sqrt(64)) * log2(e)
  const float C2 = 11.54156036f;  // 8 * log2(e)  (fixed shift; scores bounded)

  // Stage K tile (64x64 u16 = 512 x 16B chunks, 2 per thread), pre-swizzled src.
#define STAGE_K(nb, kbn) do {                                                  \
    _Pragma("unroll")                                                          \
    for (int r2 = 0; r2 < 2; ++r2) {                                           \
      int c = r2 * 256 + wv * 64 + lane;                                       \
      int row = c >> 3;                                                        \
      int scol = (((c & 7) * 16) ^ ((row & 7) << 4)) >> 1;                     \
      gload_lds16(Kh + base + (size_t)((kbn) + row) * DK_ + scol,              \
                  (void*)(Kt[nb] + (r2 * 256 + wv * 64) * 8));                 \
    }                                                                          \
  } while (0)

  STAGE_K(0, 0);
  __syncthreads();

  for (int kb = 0; kb < S_; kb += 64) {
    const int cur = (kb >> 6) & 1;
    if (kb + 64 < S_) STAGE_K(cur ^ 1, kb + 64);
    // ---- V loads early (global->reg; consumed after QK+softmax) ----
    bf16x8 vf[2][4];
#pragma unroll
    for (int ks = 0; ks < 2; ++ks)
#pragma unroll
      for (int n = 0; n < 4; ++n)
        vf[ks][n] = *(const bf16x8*)(Vt + ((size_t)bh * DK_ + n * 16 + lr) * S_
                                     + kb + ks * 32 + lk);
    // ---- K fragments from LDS (swizzled, 2-way conflict = free) ----
    bf16x8 kf[4][2];
#pragma unroll
    for (int f = 0; f < 4; ++f)
#pragma unroll
      for (int half = 0; half < 2; ++half) {
        const int swk = ((half * 64 + g * 16) ^ ((lr & 7) << 4)) >> 1;
        kf[f][half] = *(const bf16x8*)(Kt[cur] + (f * 16 + lr) * 64 + swk);
      }
    // ---- QK^T swapped: sc[f][m] rows=keys f*16+g*4+r, col=q m*16+lr ----
    f32x4 sc[4][2];
#pragma unroll
    for (int f = 0; f < 4; ++f) {
      sc[f][0] = (f32x4){0.f, 0.f, 0.f, 0.f};
      sc[f][1] = (f32x4){0.f, 0.f, 0.f, 0.f};
    }
#pragma unroll
    for (int f = 0; f < 4; ++f) {
      sc[f][0] = __builtin_amdgcn_mfma_f32_16x16x32_bf16(kf[f][0], qf[0][0], sc[f][0], 0, 0, 0);
      sc[f][0] = __builtin_amdgcn_mfma_f32_16x16x32_bf16(kf[f][1], qf[0][1], sc[f][0], 0, 0, 0);
      sc[f][1] = __builtin_amdgcn_mfma_f32_16x16x32_bf16(kf[f][0], qf[1][0], sc[f][1], 0, 0, 0);
      sc[f][1] = __builtin_amdgcn_mfma_f32_16x16x32_bf16(kf[f][1], qf[1][1], sc[f][1], 0, 0, 0);
    }
    // ---- fixed-shift softmax + pack + LDS write (keys r-contiguous) ----
#pragma unroll
    for (int m = 0; m < 2; ++m) {
      const int row = m * 16 + lr;
#pragma unroll
      for (int f = 0; f < 4; ++f) {
        f32x4 p;
        p[0] = __builtin_amdgcn_exp2f(fmaf(sc[f][m][0], C1, -C2));
        p[1] = __builtin_amdgcn_exp2f(fmaf(sc[f][m][1], C1, -C2));
        p[2] = __builtin_amdgcn_exp2f(fmaf(sc[f][m][2], C1, -C2));
        p[3] = __builtin_amdgcn_exp2f(fmaf(sc[f][m][3], C1, -C2));
        lsum[m] += p;
        uint2 w;
        w.x = cvt_pk_bf16(p[0], p[1]);
        w.y = cvt_pk_bf16(p[2], p[3]);
        *(uint2*)(Pw + row * 72 + ((f * 16 + g * 4) ^ swzm)) = w;
      }
    }
    // ---- PV: O[q][d] += P * V.  A=P from LDS, B=V (already in regs) ----
    bf16x8 pa[2][2];
#pragma unroll
    for (int m = 0; m < 2; ++m)
#pragma unroll
      for (int ks = 0; ks < 2; ++ks)
        pa[m][ks] = *(const bf16x8*)(Pw + (m * 16 + lr) * 72 + ((ks * 32 + lk) ^ swzm));
#pragma unroll
    for (int ks = 0; ks < 2; ++ks)
#pragma unroll
      for (int n = 0; n < 4; ++n) {
        acc[0][n] = __builtin_amdgcn_mfma_f32_16x16x32_bf16(pa[0][ks], vf[ks][n], acc[0][n], 0, 0, 0);
        acc[1][n] = __builtin_amdgcn_mfma_f32_16x16x32_bf16(pa[1][ks], vf[ks][n], acc[1][n], 0, 0, 0);
      }
    __syncthreads();   // drains K staging; all waves done reading Kt[cur]
  }
#undef STAGE_K

  // ---- epilogue: row sums (2 shfl), redistribute, normalize ----
#pragma unroll
  for (int m = 0; m < 2; ++m) {
    float s = lsum[m][0] + lsum[m][1] + lsum[m][2] + lsum[m][3];
    s += __shfl_xor(s, 16);
    s += __shfl_xor(s, 32);           // now s = total for q-row m*16+lr, all lanes
#pragma unroll
    for (int r = 0; r < 4; ++r) {
      float inv = 1.0f / __shfl(s, g * 4 + r);   // sum for q-row m*16+g*4+r
      int row = b * S_ + qrow + m * 16 + g * 4 + r;
#pragma unroll
      for (int n = 0; n < 4; ++n)
        Oout[(size_t)row * D_ + h * 64 + n * 16 + lr] = f2bf(acc[m][n][r] * inv);
    }
  }
}

extern "C" void kernel_launch(void* const* d_in, const int* in_sizes, int n_in,
                              void* d_out, int out_size, void* d_ws, size_t ws_size,
                              hipStream_t stream) {
  const float* q    = (const float*)d_in[0];
  const float* k    = (const float*)d_in[1];
  const float* v    = (const float*)d_in[2];
  const float* Wq_w = (const float*)d_in[3];
  const float* Wq_b = (const float*)d_in[4];
  const float* Wk_w = (const float*)d_in[5];
  const float* Wk_b = (const float*)d_in[6];
  const float* Wv_w = (const float*)d_in[7];
  const float* Wv_b = (const float*)d_in[8];
  const float* Wo_w = (const float*)d_in[9];
  const float* Wo_b = (const float*)d_in[10];

  // -------- workspace layout: 40 MB total, phased aliasing --------
  char* ws = (char*)d_ws;
  const size_t MB = 1024 * 1024;
  float* cosT = (float*)(ws);            //  4 MB  (2048*512 f32)
  float* sinT = (float*)(ws + 4 * MB);   //  4 MB
  u16* qr  = (u16*)(ws + 8 * MB);        //  8 MB  (4096x1024 bf16)
  u16* kr  = (u16*)(ws + 16 * MB);       //  8 MB
  u16* vb  = (u16*)(ws + 24 * MB);       //  8 MB
  u16* Wqh = (u16*)(ws + 32 * MB);       //  2 MB
  u16* Wkh = (u16*)(ws + 34 * MB);       //  2 MB
  u16* Wvh = (u16*)(ws + 36 * MB);       //  2 MB
  u16* Woh = (u16*)(ws + 38 * MB);       //  2 MB
  u16* Qh  = (u16*)(ws);                 //  8 MB (B,H,S,DK)  [over tables]
  u16* Kh  = (u16*)(ws + 8 * MB);        //  8 MB (B,H,S,DK)  [over qr]
  u16* Vt  = (u16*)(ws + 16 * MB);       //  8 MB (B,H,DK,S)  [over kr]
  u16* attn_o = (u16*)(ws + 24 * MB);    //  8 MB             [over vb]

  rope_tables_k<<<dim3(S_ * 512 / 256), dim3(256), 0, stream>>>(cosT, sinT);
  rope_apply<<<dim3(B_ * S_), dim3(256), 0, stream>>>(q, k, v, cosT, sinT, qr, kr, vb);

  cvt4_k<<<dim3(4 * D_ * D_ / 4 / 256), dim3(256), 0, stream>>>(Wq_w, Wk_w, Wv_w, Wo_w, Wqh);

  const int M = B_ * S_, N = D_, K = D_;
  dim3 ggrid((M / 128) * (N / 64));      // 512 blocks = 2/CU
  // Order matters for the aliasing: Q-GEMM frees qr before Kh is written, etc.
  gemm_bt2<<<ggrid, dim3(256), 0, stream>>>(qr, Wqh, Wq_b, (void*)Qh, M, N, K, 0);
  gemm_bt2<<<ggrid, dim3(256), 0, stream>>>(kr, Wkh, Wk_b, (void*)Kh, M, N, K, 0);
  gemm_bt2<<<ggrid, dim3(256), 0, stream>>>(vb, Wvh, Wv_b, (void*)Vt, M, N, K, 1);

  attn_kernel<<<dim3(B_ * H_ * (S_ / 128)), dim3(256), 0, stream>>>(Qh, Kh, Vt, attn_o);

  gemm_bt2<<<ggrid, dim3(256), 0, stream>>>(attn_o, Woh, Wo_b, d_out, M, N, K, 2);
}

// Round 10
// 259.715 us; speedup vs baseline: 1.1187x; 1.1187x over previous
//
#include <hip/hip_runtime.h>
#include <hip/hip_bf16.h>
#include <cstdint>

// Problem constants (fixed by setup_inputs)
#define B_  2
#define S_  2048
#define D_  1024
#define H_  16
#define DK_ 64

typedef unsigned short u16;
typedef __attribute__((ext_vector_type(8))) __bf16 bf16x8;
typedef __attribute__((ext_vector_type(4))) float  f32x4;

__device__ __forceinline__ u16 f2bf(float f) {
  union { float f; uint32_t u; } x; x.f = f;
  uint32_t r = (x.u + 0x7fffu + ((x.u >> 16) & 1u)) >> 16;  // RNE
  return (u16)r;
}

// v_cvt_pk_bf16_f32: D.lo = bf16(lo), D.hi = bf16(hi). No builtin on gfx950 (m240).
__device__ __forceinline__ uint32_t cvt_pk_bf16(float lo, float hi) {
  uint32_t r;
  asm volatile("v_cvt_pk_bf16_f32 %0, %1, %2" : "=v"(r) : "v"(lo), "v"(hi));
  return r;
}

__device__ __forceinline__ void gload_lds16(const void* g, void* l) {
  __builtin_amdgcn_global_load_lds(
      (const __attribute__((address_space(1))) void*)g,
      (__attribute__((address_space(3))) void*)l, 16, 0, 0);
}

// ---------------- RoPE apply (tables fused; fp64 range-reduce + HW sincos) ----
// theta_i = 1e4^(-2i/D) = 2^(i*c2). Split i*c2 = fl + fr (fp64 exact ops),
// theta = ldexp(exp2f(fr), fl)  (rel err ~1e-7 -> arg err <= 2e-4 rad, within
// budget). Angle reduced in fp64 revolutions (mul/floor only), sin/cos via HW.
__device__ __forceinline__ void rope_cs(int i, int pos, float& c, float& s) {
  double t  = (double)i * (-0.02595256324130751);   // -2*log2(1e4)/1024
  double fl = floor(t);
  float  m2 = exp2f((float)(t - fl));
  double theta = ldexp((double)m2, (int)fl);
  double u  = (double)pos * theta * 0.15915494309189535;  // revolutions
  double uf = u - floor(u);
  float  xr = (float)uf * 6.283185307179586f;
  c = __cosf(xr);
  s = __sinf(xr);
}

__global__ __launch_bounds__(256) void rope_apply(
    const float* __restrict__ q, const float* __restrict__ k, const float* __restrict__ v,
    u16* __restrict__ qr, u16* __restrict__ kr, u16* __restrict__ vb) {
  const int row = blockIdx.x;        // 0..B_*S_-1
  const int j   = threadIdx.x;       // 0..255 (pair index)
  const int s   = row & (S_ - 1);
  float c0, s0, c1, s1;
  rope_cs(j,       s + 1, c0, s0);
  rope_cs(j + 256, s + 1, c1, s1);
  const size_t off = (size_t)row * D_;

  float2 qa = *(const float2*)(q + off + 2 * j);
  float2 qb = *(const float2*)(q + off + 2 * j + 512);
  qr[off + 2*j]       = f2bf(qa.x * c0 - qb.x * s0);
  qr[off + 2*j + 1]   = f2bf(qa.y * c0 - qb.y * s0);
  qr[off + 2*j + 512] = f2bf(qb.x * c1 + qa.x * s1);
  qr[off + 2*j + 513] = f2bf(qb.y * c1 + qa.y * s1);

  float2 ka = *(const float2*)(k + off + 2 * j);
  float2 kb = *(const float2*)(k + off + 2 * j + 512);
  kr[off + 2*j]       = f2bf(ka.x * c0 - kb.x * s0);
  kr[off + 2*j + 1]   = f2bf(ka.y * c0 - kb.y * s0);
  kr[off + 2*j + 512] = f2bf(kb.x * c1 + ka.x * s1);
  kr[off + 2*j + 513] = f2bf(kb.y * c1 + ka.y * s1);

  float2 va = *(const float2*)(v + off + 2 * j);
  float2 vv = *(const float2*)(v + off + 2 * j + 512);
  vb[off + 2*j]       = f2bf(va.x);
  vb[off + 2*j + 1]   = f2bf(va.y);
  vb[off + 2*j + 512] = f2bf(vv.x);
  vb[off + 2*j + 513] = f2bf(vv.y);
}

// ---------------- weight fp32 -> bf16 (all four in one launch) ----------------
__global__ __launch_bounds__(256) void cvt4_k(const float* __restrict__ w0,
                                              const float* __restrict__ w1,
                                              const float* __restrict__ w2,
                                              const float* __restrict__ w3,
                                              u16* __restrict__ out) {
  int i = (blockIdx.x * 256 + threadIdx.x) * 4;   // 4*D_*D_ elements total
  int which = i >> 20;                            // 1M elements per matrix
  const float* src = which == 0 ? w0 : which == 1 ? w1 : which == 2 ? w2 : w3;
  float4 f = *(const float4*)(src + (i & 1048575));
  out[i]     = f2bf(f.x);
  out[i + 1] = f2bf(f.y);
  out[i + 2] = f2bf(f.z);
  out[i + 3] = f2bf(f.w);
}

// ---------------- fused QKV GEMM ----------------
// A = concat(qr,kr,vb) (12288 x 1024, contiguous at ws+8MB). Segment by
// tileM>>12 selects W/bias/output/mode. Grid 1536 = 6 blocks/CU (LDS 24KB,
// launch_bounds(256,6)): round-9 showed 2/CU == 1/CU (per-CU pipe-bound at
// 8 waves/CU); 24 waves/CU overlaps LDS/L2/VALU/MFMA pipes across waves.
// K-loop structure = gemm_bt2 (round-9 proven). V epilogue: 4 m-consecutive
// bf16 packed into one 8B store (old path: 4 scattered 2B stores -> ~8x
// write amplification on 64B lines).
__global__ __launch_bounds__(256, 6) void gemm_qkv(
    const u16* __restrict__ Aall, const u16* __restrict__ Wall,
    const float* __restrict__ bq, const float* __restrict__ bk,
    const float* __restrict__ bv,
    u16* __restrict__ Qh, u16* __restrict__ Kh, u16* __restrict__ Vt) {
  __shared__ __align__(16) u16 At[2][128 * 32];
  __shared__ __align__(16) u16 Bt[2][64 * 32];
  const int tid  = threadIdx.x;
  const int lane = tid & 63;
  const int wv   = tid >> 6;
  const int wm   = wv >> 1, wn = wv & 1;   // wave tile 64x32
  // XCD chunking: 1536 blocks, 192 consecutive per XCD.
  const int sw = (blockIdx.x & 7) * 192 + (blockIdx.x >> 3);
  const int mt = sw >> 4;                  // 0..95 (M-tile in concat space)
  const int tileM = mt * 128;
  const int tileN = (sw & 15) * 64;
  const int seg = mt >> 5;                 // 0:Q 1:K 2:V
  const u16* W = Wall + (size_t)seg * D_ * D_;
  const float* bias = seg == 0 ? bq : (seg == 1 ? bk : bv);
  const int lr = lane & 15;
  const int g  = lane >> 4;
  const int K = D_;

  f32x4 acc[4][2];
#pragma unroll
  for (int i = 0; i < 4; ++i)
#pragma unroll
    for (int j = 0; j < 2; ++j) acc[i][j] = (f32x4){0.f, 0.f, 0.f, 0.f};

  // Hoisted staging addresses (loop-invariant except +kbn).
  const int ca0 = tid, ca1 = 256 + tid, cb = tid;
  const int ra0 = ca0 >> 2, ra1 = ca1 >> 2, rb = cb >> 2;
  const int sa0 = ((ca0 & 3) ^ ((ra0 >> 1) & 3)) * 8;
  const int sa1 = ((ca1 & 3) ^ ((ra1 >> 1) & 3)) * 8;
  const int sb  = ((cb  & 3) ^ ((rb  >> 1) & 3)) * 8;
  const u16* pa0 = Aall + (size_t)(tileM + ra0) * K + sa0;
  const u16* pa1 = Aall + (size_t)(tileM + ra1) * K + sa1;
  const u16* pb  = W    + (size_t)(tileN + rb)  * K + sb;

#define GSTAGE(buf, kbn) do {                                                  \
    gload_lds16(pa0 + (kbn), (void*)(At[buf] + (wv * 64) * 8));                \
    gload_lds16(pa1 + (kbn), (void*)(At[buf] + (256 + wv * 64) * 8));          \
    gload_lds16(pb  + (kbn), (void*)(Bt[buf] + (wv * 64) * 8));                \
  } while (0)

  GSTAGE(0, 0);
  __syncthreads();
  for (int kb = 0; kb < K; kb += 32) {
    const int cur = (kb >> 5) & 1;
    if (kb + 32 < K) GSTAGE(cur ^ 1, kb + 32);
    bf16x8 af[4], bfr[2];
#pragma unroll
    for (int i = 0; i < 4; ++i) {
      int r = wm * 64 + i * 16 + lr;
      af[i] = *(const bf16x8*)(At[cur] + r * 32 + (g ^ ((r >> 1) & 3)) * 8);
    }
#pragma unroll
    for (int i = 0; i < 2; ++i) {
      int r = wn * 32 + i * 16 + lr;
      bfr[i] = *(const bf16x8*)(Bt[cur] + r * 32 + (g ^ ((r >> 1) & 3)) * 8);
    }
#pragma unroll
    for (int mi = 0; mi < 4; ++mi)
#pragma unroll
      for (int ni = 0; ni < 2; ++ni)
        acc[mi][ni] = __builtin_amdgcn_mfma_f32_16x16x32_bf16(af[mi], bfr[ni],
                                                              acc[mi][ni], 0, 0, 0);
    __syncthreads();
  }
#undef GSTAGE

  // Epilogue. D-layout (m89-verified): col = lane&15, row = (lane>>4)*4 + reg
#pragma unroll
  for (int mi = 0; mi < 4; ++mi)
#pragma unroll
    for (int ni = 0; ni < 2; ++ni) {
      const int n  = tileN + wn * 32 + ni * 16 + lr;
      const int hh = n >> 6, dk = n & 63;
      const float bval = bias[n];
      const int m0 = tileM + wm * 64 + mi * 16 + g * 4;   // concat row, r=0
      const int mloc = m0 & 4095;
      const int bb = mloc >> 11, ss = mloc & (S_ - 1);
      if (seg == 2) {
        // V: pack 4 ss-consecutive bf16 -> one 8B store into Vt (B,H,DK,S)
        uint2 w;
        w.x = cvt_pk_bf16(acc[mi][ni][0] + bval, acc[mi][ni][1] + bval);
        w.y = cvt_pk_bf16(acc[mi][ni][2] + bval, acc[mi][ni][3] + bval);
        *(uint2*)(Vt + (((size_t)(bb * H_ + hh) * DK_ + dk) << 11) + ss) = w;
      } else {
        u16* dst = (seg == 0 ? Qh : Kh);
#pragma unroll
        for (int r = 0; r < 4; ++r)
          dst[(((size_t)(bb * H_ + hh) * S_ + ss + r) << 6) + dk] =
              f2bf(acc[mi][ni][r] + bval);
      }
    }
}

// ---------------- output GEMM: C = A(M,K) * W(N,K)^T + bias (fp32 out) -------
// round-9 proven gemm_bt2, mode-2 path only.
__global__ __launch_bounds__(256) void gemm_out(
    const u16* __restrict__ A, const u16* __restrict__ W,
    const float* __restrict__ bias, float* __restrict__ out,
    int M, int N, int K) {
  __shared__ __align__(16) u16 At[2][128 * 32];
  __shared__ __align__(16) u16 Bt[2][64 * 32];
  const int tid  = threadIdx.x;
  const int lane = tid & 63;
  const int wv   = tid >> 6;
  const int wm   = wv >> 1, wn = wv & 1;
  const int sw = (blockIdx.x & 7) * 64 + (blockIdx.x >> 3);
  const int tileM = (sw >> 4) * 128;
  const int tileN = (sw & 15) * 64;
  const int lr = lane & 15;
  const int g  = lane >> 4;

  f32x4 acc[4][2];
#pragma unroll
  for (int i = 0; i < 4; ++i)
#pragma unroll
    for (int j = 0; j < 2; ++j) acc[i][j] = (f32x4){0.f, 0.f, 0.f, 0.f};

  const int ca0 = tid, ca1 = 256 + tid, cb = tid;
  const int ra0 = ca0 >> 2, ra1 = ca1 >> 2, rb = cb >> 2;
  const int sa0 = ((ca0 & 3) ^ ((ra0 >> 1) & 3)) * 8;
  const int sa1 = ((ca1 & 3) ^ ((ra1 >> 1) & 3)) * 8;
  const int sb  = ((cb  & 3) ^ ((rb  >> 1) & 3)) * 8;
  const u16* pa0 = A + (size_t)(tileM + ra0) * K + sa0;
  const u16* pa1 = A + (size_t)(tileM + ra1) * K + sa1;
  const u16* pb  = W + (size_t)(tileN + rb)  * K + sb;

#define GSTAGE(buf, kbn) do {                                                  \
    gload_lds16(pa0 + (kbn), (void*)(At[buf] + (wv * 64) * 8));                \
    gload_lds16(pa1 + (kbn), (void*)(At[buf] + (256 + wv * 64) * 8));          \
    gload_lds16(pb  + (kbn), (void*)(Bt[buf] + (wv * 64) * 8));                \
  } while (0)

  GSTAGE(0, 0);
  __syncthreads();
  for (int kb = 0; kb < K; kb += 32) {
    const int cur = (kb >> 5) & 1;
    if (kb + 32 < K) GSTAGE(cur ^ 1, kb + 32);
    bf16x8 af[4], bfr[2];
#pragma unroll
    for (int i = 0; i < 4; ++i) {
      int r = wm * 64 + i * 16 + lr;
      af[i] = *(const bf16x8*)(At[cur] + r * 32 + (g ^ ((r >> 1) & 3)) * 8);
    }
#pragma unroll
    for (int i = 0; i < 2; ++i) {
      int r = wn * 32 + i * 16 + lr;
      bfr[i] = *(const bf16x8*)(Bt[cur] + r * 32 + (g ^ ((r >> 1) & 3)) * 8);
    }
#pragma unroll
    for (int mi = 0; mi < 4; ++mi)
#pragma unroll
      for (int ni = 0; ni < 2; ++ni)
        acc[mi][ni] = __builtin_amdgcn_mfma_f32_16x16x32_bf16(af[mi], bfr[ni],
                                                              acc[mi][ni], 0, 0, 0);
    __syncthreads();
  }
#undef GSTAGE

#pragma unroll
  for (int mi = 0; mi < 4; ++mi)
#pragma unroll
    for (int ni = 0; ni < 2; ++ni)
#pragma unroll
      for (int r = 0; r < 4; ++r) {
        int m = tileM + wm * 64 + mi * 16 + g * 4 + r;
        int n = tileN + wn * 32 + ni * 16 + lr;
        out[(size_t)m * N + n] = acc[mi][ni][r] + bias[n];
      }
}

// ---------------- flash attention v5 (round-7/9 proven, verbatim) -------------
__global__ __launch_bounds__(256, 2) void attn_kernel(
    const u16* __restrict__ Qh, const u16* __restrict__ Kh,
    const u16* __restrict__ Vt, u16* __restrict__ Oout) {
  __shared__ __align__(16) u16 Kt[2][64 * 64];     // [buf][row][64 u16] 8KB each
  __shared__ __align__(16) u16 Plds[4][32 * 72];   // per-wave P staging
  const int lane = threadIdx.x & 63;
  const int wv   = threadIdx.x >> 6;
  const int lr = lane & 15, g = lane >> 4, lk = g * 8;
  const int swzm = (lr & 3) << 4;                  // P-staging col XOR mask
  const int sw = (blockIdx.x & 7) * 64 + (blockIdx.x >> 3);
  const int bh = sw >> 4;                          // 0..31
  const int qb = (sw & 15) * 128;
  const int b = bh >> 4, h = bh & 15;
  const size_t base = (size_t)bh * S_ * DK_;
  const int qrow = qb + wv * 32;
  u16* Pw = &Plds[wv][0];

  bf16x8 qf[2][2];
#pragma unroll
  for (int m = 0; m < 2; ++m)
#pragma unroll
    for (int i = 0; i < 2; ++i)
      qf[m][i] = *(const bf16x8*)(Qh + base + (size_t)(qrow + m * 16 + lr) * DK_ + i * 32 + lk);

  f32x4 acc[2][4];
  f32x4 lsum[2];
#pragma unroll
  for (int m = 0; m < 2; ++m) {
    lsum[m] = (f32x4){0.f, 0.f, 0.f, 0.f};
#pragma unroll
    for (int n = 0; n < 4; ++n) acc[m][n] = (f32x4){0.f, 0.f, 0.f, 0.f};
  }

  const float C1 = 0.18033688f;   // (1/sqrt(64)) * log2(e)
  const float C2 = 11.54156036f;  // 8 * log2(e)  (fixed shift; scores bounded)

#define STAGE_K(nb, kbn) do {                                                  \
    _Pragma("unroll")                                                          \
    for (int r2 = 0; r2 < 2; ++r2) {                                           \
      int c = r2 * 256 + wv * 64 + lane;                                       \
      int row = c >> 3;                                                        \
      int scol = (((c & 7) * 16) ^ ((row & 7) << 4)) >> 1;                     \
      gload_lds16(Kh + base + (size_t)((kbn) + row) * DK_ + scol,              \
                  (void*)(Kt[nb] + (r2 * 256 + wv * 64) * 8));                 \
    }                                                                          \
  } while (0)

  STAGE_K(0, 0);
  __syncthreads();

  for (int kb = 0; kb < S_; kb += 64) {
    const int cur = (kb >> 6) & 1;
    if (kb + 64 < S_) STAGE_K(cur ^ 1, kb + 64);
    bf16x8 vf[2][4];
#pragma unroll
    for (int ks = 0; ks < 2; ++ks)
#pragma unroll
      for (int n = 0; n < 4; ++n)
        vf[ks][n] = *(const bf16x8*)(Vt + ((size_t)bh * DK_ + n * 16 + lr) * S_
                                     + kb + ks * 32 + lk);
    bf16x8 kf[4][2];
#pragma unroll
    for (int f = 0; f < 4; ++f)
#pragma unroll
      for (int half = 0; half < 2; ++half) {
        const int swk = ((half * 64 + g * 16) ^ ((lr & 7) << 4)) >> 1;
        kf[f][half] = *(const bf16x8*)(Kt[cur] + (f * 16 + lr) * 64 + swk);
      }
    f32x4 sc[4][2];
#pragma unroll
    for (int f = 0; f < 4; ++f) {
      sc[f][0] = (f32x4){0.f, 0.f, 0.f, 0.f};
      sc[f][1] = (f32x4){0.f, 0.f, 0.f, 0.f};
    }
#pragma unroll
    for (int f = 0; f < 4; ++f) {
      sc[f][0] = __builtin_amdgcn_mfma_f32_16x16x32_bf16(kf[f][0], qf[0][0], sc[f][0], 0, 0, 0);
      sc[f][0] = __builtin_amdgcn_mfma_f32_16x16x32_bf16(kf[f][1], qf[0][1], sc[f][0], 0, 0, 0);
      sc[f][1] = __builtin_amdgcn_mfma_f32_16x16x32_bf16(kf[f][0], qf[1][0], sc[f][1], 0, 0, 0);
      sc[f][1] = __builtin_amdgcn_mfma_f32_16x16x32_bf16(kf[f][1], qf[1][1], sc[f][1], 0, 0, 0);
    }
#pragma unroll
    for (int m = 0; m < 2; ++m) {
      const int row = m * 16 + lr;
#pragma unroll
      for (int f = 0; f < 4; ++f) {
        f32x4 p;
        p[0] = __builtin_amdgcn_exp2f(fmaf(sc[f][m][0], C1, -C2));
        p[1] = __builtin_amdgcn_exp2f(fmaf(sc[f][m][1], C1, -C2));
        p[2] = __builtin_amdgcn_exp2f(fmaf(sc[f][m][2], C1, -C2));
        p[3] = __builtin_amdgcn_exp2f(fmaf(sc[f][m][3], C1, -C2));
        lsum[m] += p;
        uint2 w;
        w.x = cvt_pk_bf16(p[0], p[1]);
        w.y = cvt_pk_bf16(p[2], p[3]);
        *(uint2*)(Pw + row * 72 + ((f * 16 + g * 4) ^ swzm)) = w;
      }
    }
    bf16x8 pa[2][2];
#pragma unroll
    for (int m = 0; m < 2; ++m)
#pragma unroll
      for (int ks = 0; ks < 2; ++ks)
        pa[m][ks] = *(const bf16x8*)(Pw + (m * 16 + lr) * 72 + ((ks * 32 + lk) ^ swzm));
#pragma unroll
    for (int ks = 0; ks < 2; ++ks)
#pragma unroll
      for (int n = 0; n < 4; ++n) {
        acc[0][n] = __builtin_amdgcn_mfma_f32_16x16x32_bf16(pa[0][ks], vf[ks][n], acc[0][n], 0, 0, 0);
        acc[1][n] = __builtin_amdgcn_mfma_f32_16x16x32_bf16(pa[1][ks], vf[ks][n], acc[1][n], 0, 0, 0);
      }
    __syncthreads();
  }
#undef STAGE_K

#pragma unroll
  for (int m = 0; m < 2; ++m) {
    float s = lsum[m][0] + lsum[m][1] + lsum[m][2] + lsum[m][3];
    s += __shfl_xor(s, 16);
    s += __shfl_xor(s, 32);
#pragma unroll
    for (int r = 0; r < 4; ++r) {
      float inv = 1.0f / __shfl(s, g * 4 + r);
      int row = b * S_ + qrow + m * 16 + g * 4 + r;
#pragma unroll
      for (int n = 0; n < 4; ++n)
        Oout[(size_t)row * D_ + h * 64 + n * 16 + lr] = f2bf(acc[m][n][r] * inv);
    }
  }
}

extern "C" void kernel_launch(void* const* d_in, const int* in_sizes, int n_in,
                              void* d_out, int out_size, void* d_ws, size_t ws_size,
                              hipStream_t stream) {
  const float* q    = (const float*)d_in[0];
  const float* k    = (const float*)d_in[1];
  const float* v    = (const float*)d_in[2];
  const float* Wq_w = (const float*)d_in[3];
  const float* Wq_b = (const float*)d_in[4];
  const float* Wk_w = (const float*)d_in[5];
  const float* Wk_b = (const float*)d_in[6];
  const float* Wv_w = (const float*)d_in[7];
  const float* Wv_b = (const float*)d_in[8];
  const float* Wo_w = (const float*)d_in[9];
  const float* Wo_b = (const float*)d_in[10];

  // -------- workspace layout: 40 MB, plus d_out (16.78 MB) as mid-stream
  // scratch for Kh/Vt (dead until final GEMM overwrites it). Per-launch
  // read/write sets verified disjoint (fused QKV runs concurrently).
  char* ws = (char*)d_ws;
  const size_t MB = 1024 * 1024;
  u16* Qh  = (u16*)(ws);                 //  [0,8)   QKV out: Q heads
  u16* qr  = (u16*)(ws + 8 * MB);        //  [8,16)  roped q  (concat A base)
  u16* kr  = (u16*)(ws + 16 * MB);       //  [16,24) roped k
  u16* vb  = (u16*)(ws + 24 * MB);       //  [24,32) bf16 v
  u16* Wqh = (u16*)(ws + 32 * MB);       //  [32,40) 4 weights (cvt4 contiguous)
  u16* Woh = (u16*)(ws + 38 * MB);
  u16* attn_o = (u16*)(ws + 8 * MB);     //  over qr (dead after QKV GEMM)
  u16* Kh  = (u16*)d_out;                //  d_out[0, 8.39MB)   K heads
  u16* Vt  = Kh + (size_t)B_ * H_ * S_ * DK_;  // d_out[8.39, 16.78MB) V^T

  rope_apply<<<dim3(B_ * S_), dim3(256), 0, stream>>>(q, k, v, qr, kr, vb);
  cvt4_k<<<dim3(4 * D_ * D_ / 4 / 256), dim3(256), 0, stream>>>(Wq_w, Wk_w, Wv_w, Wo_w, Wqh);

  gemm_qkv<<<dim3(96 * 16), dim3(256), 0, stream>>>(qr, Wqh, Wq_b, Wk_b, Wv_b,
                                                    Qh, Kh, Vt);

  attn_kernel<<<dim3(B_ * H_ * (S_ / 128)), dim3(256), 0, stream>>>(Qh, Kh, Vt, attn_o);

  const int M = B_ * S_, N = D_, K = D_;
  gemm_out<<<dim3((M / 128) * (N / 64)), dim3(256), 0, stream>>>(
      attn_o, Woh, Wo_b, (float*)d_out, M, N, K);
}

// Round 11
// 231.152 us; speedup vs baseline: 1.2569x; 1.1236x over previous
//
#include <hip/hip_runtime.h>
#include <hip/hip_bf16.h>
#include <cstdint>

// Problem constants (fixed by setup_inputs)
#define B_  2
#define S_  2048
#define D_  1024
#define H_  16
#define DK_ 64

typedef unsigned short u16;
typedef __attribute__((ext_vector_type(8))) __bf16 bf16x8;
typedef __attribute__((ext_vector_type(4))) float  f32x4;

__device__ __forceinline__ u16 f2bf(float f) {
  union { float f; uint32_t u; } x; x.f = f;
  uint32_t r = (x.u + 0x7fffu + ((x.u >> 16) & 1u)) >> 16;  // RNE
  return (u16)r;
}

// v_cvt_pk_bf16_f32: D.lo = bf16(lo), D.hi = bf16(hi). No builtin on gfx950 (m240).
__device__ __forceinline__ uint32_t cvt_pk_bf16(float lo, float hi) {
  uint32_t r;
  asm volatile("v_cvt_pk_bf16_f32 %0, %1, %2" : "=v"(r) : "v"(lo), "v"(hi));
  return r;
}

__device__ __forceinline__ void gload_lds16(const void* g, void* l) {
  __builtin_amdgcn_global_load_lds(
      (const __attribute__((address_space(1))) void*)g,
      (__attribute__((address_space(3))) void*)l, 16, 0, 0);
}

// ---------------- RoPE apply (tables fused; fp64 range-reduce + HW sincos) ----
__device__ __forceinline__ void rope_cs(int i, int pos, float& c, float& s) {
  double t  = (double)i * (-0.02595256324130751);   // -2*log2(1e4)/1024
  double fl = floor(t);
  float  m2 = exp2f((float)(t - fl));
  double theta = ldexp((double)m2, (int)fl);
  double u  = (double)pos * theta * 0.15915494309189535;  // revolutions
  double uf = u - floor(u);
  float  xr = (float)uf * 6.283185307179586f;
  c = __cosf(xr);
  s = __sinf(xr);
}

__global__ __launch_bounds__(256) void rope_apply(
    const float* __restrict__ q, const float* __restrict__ k, const float* __restrict__ v,
    u16* __restrict__ qr, u16* __restrict__ kr, u16* __restrict__ vb) {
  const int row = blockIdx.x;        // 0..B_*S_-1
  const int j   = threadIdx.x;       // 0..255 (pair index)
  const int s   = row & (S_ - 1);
  float c0, s0, c1, s1;
  rope_cs(j,       s + 1, c0, s0);
  rope_cs(j + 256, s + 1, c1, s1);
  const size_t off = (size_t)row * D_;

  float2 qa = *(const float2*)(q + off + 2 * j);
  float2 qb = *(const float2*)(q + off + 2 * j + 512);
  qr[off + 2*j]       = f2bf(qa.x * c0 - qb.x * s0);
  qr[off + 2*j + 1]   = f2bf(qa.y * c0 - qb.y * s0);
  qr[off + 2*j + 512] = f2bf(qb.x * c1 + qa.x * s1);
  qr[off + 2*j + 513] = f2bf(qb.y * c1 + qa.y * s1);

  float2 ka = *(const float2*)(k + off + 2 * j);
  float2 kb = *(const float2*)(k + off + 2 * j + 512);
  kr[off + 2*j]       = f2bf(ka.x * c0 - kb.x * s0);
  kr[off + 2*j + 1]   = f2bf(ka.y * c0 - kb.y * s0);
  kr[off + 2*j + 512] = f2bf(kb.x * c1 + ka.x * s1);
  kr[off + 2*j + 513] = f2bf(kb.y * c1 + ka.y * s1);

  float2 va = *(const float2*)(v + off + 2 * j);
  float2 vv = *(const float2*)(v + off + 2 * j + 512);
  vb[off + 2*j]       = f2bf(va.x);
  vb[off + 2*j + 1]   = f2bf(va.y);
  vb[off + 2*j + 512] = f2bf(vv.x);
  vb[off + 2*j + 513] = f2bf(vv.y);
}

// ---------------- weight fp32 -> bf16 (all four in one launch) ----------------
__global__ __launch_bounds__(256) void cvt4_k(const float* __restrict__ w0,
                                              const float* __restrict__ w1,
                                              const float* __restrict__ w2,
                                              const float* __restrict__ w3,
                                              u16* __restrict__ out) {
  int i = (blockIdx.x * 256 + threadIdx.x) * 4;   // 4*D_*D_ elements total
  int which = i >> 20;                            // 1M elements per matrix
  const float* src = which == 0 ? w0 : which == 1 ? w1 : which == 2 ? w2 : w3;
  float4 f = *(const float4*)(src + (i & 1048575));
  out[i]     = f2bf(f.x);
  out[i + 1] = f2bf(f.y);
  out[i + 2] = f2bf(f.z);
  out[i + 3] = f2bf(f.w);
}

// ---------------- fused QKV GEMM (round-10 proven, verbatim) ----------------
__global__ __launch_bounds__(256, 6) void gemm_qkv(
    const u16* __restrict__ Aall, const u16* __restrict__ Wall,
    const float* __restrict__ bq, const float* __restrict__ bk,
    const float* __restrict__ bv,
    u16* __restrict__ Qh, u16* __restrict__ Kh, u16* __restrict__ Vt) {
  __shared__ __align__(16) u16 At[2][128 * 32];
  __shared__ __align__(16) u16 Bt[2][64 * 32];
  const int tid  = threadIdx.x;
  const int lane = tid & 63;
  const int wv   = tid >> 6;
  const int wm   = wv >> 1, wn = wv & 1;   // wave tile 64x32
  const int sw = (blockIdx.x & 7) * 192 + (blockIdx.x >> 3);
  const int mt = sw >> 4;                  // 0..95 (M-tile in concat space)
  const int tileM = mt * 128;
  const int tileN = (sw & 15) * 64;
  const int seg = mt >> 5;                 // 0:Q 1:K 2:V
  const u16* W = Wall + (size_t)seg * D_ * D_;
  const float* bias = seg == 0 ? bq : (seg == 1 ? bk : bv);
  const int lr = lane & 15;
  const int g  = lane >> 4;
  const int K = D_;

  f32x4 acc[4][2];
#pragma unroll
  for (int i = 0; i < 4; ++i)
#pragma unroll
    for (int j = 0; j < 2; ++j) acc[i][j] = (f32x4){0.f, 0.f, 0.f, 0.f};

  const int ca0 = tid, ca1 = 256 + tid, cb = tid;
  const int ra0 = ca0 >> 2, ra1 = ca1 >> 2, rb = cb >> 2;
  const int sa0 = ((ca0 & 3) ^ ((ra0 >> 1) & 3)) * 8;
  const int sa1 = ((ca1 & 3) ^ ((ra1 >> 1) & 3)) * 8;
  const int sb  = ((cb  & 3) ^ ((rb  >> 1) & 3)) * 8;
  const u16* pa0 = Aall + (size_t)(tileM + ra0) * K + sa0;
  const u16* pa1 = Aall + (size_t)(tileM + ra1) * K + sa1;
  const u16* pb  = W    + (size_t)(tileN + rb)  * K + sb;

#define GSTAGE(buf, kbn) do {                                                  \
    gload_lds16(pa0 + (kbn), (void*)(At[buf] + (wv * 64) * 8));                \
    gload_lds16(pa1 + (kbn), (void*)(At[buf] + (256 + wv * 64) * 8));          \
    gload_lds16(pb  + (kbn), (void*)(Bt[buf] + (wv * 64) * 8));                \
  } while (0)

  GSTAGE(0, 0);
  __syncthreads();
  for (int kb = 0; kb < K; kb += 32) {
    const int cur = (kb >> 5) & 1;
    if (kb + 32 < K) GSTAGE(cur ^ 1, kb + 32);
    bf16x8 af[4], bfr[2];
#pragma unroll
    for (int i = 0; i < 4; ++i) {
      int r = wm * 64 + i * 16 + lr;
      af[i] = *(const bf16x8*)(At[cur] + r * 32 + (g ^ ((r >> 1) & 3)) * 8);
    }
#pragma unroll
    for (int i = 0; i < 2; ++i) {
      int r = wn * 32 + i * 16 + lr;
      bfr[i] = *(const bf16x8*)(Bt[cur] + r * 32 + (g ^ ((r >> 1) & 3)) * 8);
    }
#pragma unroll
    for (int mi = 0; mi < 4; ++mi)
#pragma unroll
      for (int ni = 0; ni < 2; ++ni)
        acc[mi][ni] = __builtin_amdgcn_mfma_f32_16x16x32_bf16(af[mi], bfr[ni],
                                                              acc[mi][ni], 0, 0, 0);
    __syncthreads();
  }
#undef GSTAGE

  // Epilogue. D-layout (m89-verified): col = lane&15, row = (lane>>4)*4 + reg
#pragma unroll
  for (int mi = 0; mi < 4; ++mi)
#pragma unroll
    for (int ni = 0; ni < 2; ++ni) {
      const int n  = tileN + wn * 32 + ni * 16 + lr;
      const int hh = n >> 6, dk = n & 63;
      const float bval = bias[n];
      const int m0 = tileM + wm * 64 + mi * 16 + g * 4;   // concat row, r=0
      const int mloc = m0 & 4095;
      const int bb = mloc >> 11, ss = mloc & (S_ - 1);
      if (seg == 2) {
        uint2 w;
        w.x = cvt_pk_bf16(acc[mi][ni][0] + bval, acc[mi][ni][1] + bval);
        w.y = cvt_pk_bf16(acc[mi][ni][2] + bval, acc[mi][ni][3] + bval);
        *(uint2*)(Vt + (((size_t)(bb * H_ + hh) * DK_ + dk) << 11) + ss) = w;
      } else {
        u16* dst = (seg == 0 ? Qh : Kh);
#pragma unroll
        for (int r = 0; r < 4; ++r)
          dst[(((size_t)(bb * H_ + hh) * S_ + ss + r) << 6) + dk] =
              f2bf(acc[mi][ni][r] + bval);
      }
    }
}

// ---------------- output GEMM (round-9/10 proven, verbatim) -------------------
__global__ __launch_bounds__(256) void gemm_out(
    const u16* __restrict__ A, const u16* __restrict__ W,
    const float* __restrict__ bias, float* __restrict__ out,
    int M, int N, int K) {
  __shared__ __align__(16) u16 At[2][128 * 32];
  __shared__ __align__(16) u16 Bt[2][64 * 32];
  const int tid  = threadIdx.x;
  const int lane = tid & 63;
  const int wv   = tid >> 6;
  const int wm   = wv >> 1, wn = wv & 1;
  const int sw = (blockIdx.x & 7) * 64 + (blockIdx.x >> 3);
  const int tileM = (sw >> 4) * 128;
  const int tileN = (sw & 15) * 64;
  const int lr = lane & 15;
  const int g  = lane >> 4;

  f32x4 acc[4][2];
#pragma unroll
  for (int i = 0; i < 4; ++i)
#pragma unroll
    for (int j = 0; j < 2; ++j) acc[i][j] = (f32x4){0.f, 0.f, 0.f, 0.f};

  const int ca0 = tid, ca1 = 256 + tid, cb = tid;
  const int ra0 = ca0 >> 2, ra1 = ca1 >> 2, rb = cb >> 2;
  const int sa0 = ((ca0 & 3) ^ ((ra0 >> 1) & 3)) * 8;
  const int sa1 = ((ca1 & 3) ^ ((ra1 >> 1) & 3)) * 8;
  const int sb  = ((cb  & 3) ^ ((rb  >> 1) & 3)) * 8;
  const u16* pa0 = A + (size_t)(tileM + ra0) * K + sa0;
  const u16* pa1 = A + (size_t)(tileM + ra1) * K + sa1;
  const u16* pb  = W + (size_t)(tileN + rb)  * K + sb;

#define GSTAGE(buf, kbn) do {                                                  \
    gload_lds16(pa0 + (kbn), (void*)(At[buf] + (wv * 64) * 8));                \
    gload_lds16(pa1 + (kbn), (void*)(At[buf] + (256 + wv * 64) * 8));          \
    gload_lds16(pb  + (kbn), (void*)(Bt[buf] + (wv * 64) * 8));                \
  } while (0)

  GSTAGE(0, 0);
  __syncthreads();
  for (int kb = 0; kb < K; kb += 32) {
    const int cur = (kb >> 5) & 1;
    if (kb + 32 < K) GSTAGE(cur ^ 1, kb + 32);
    bf16x8 af[4], bfr[2];
#pragma unroll
    for (int i = 0; i < 4; ++i) {
      int r = wm * 64 + i * 16 + lr;
      af[i] = *(const bf16x8*)(At[cur] + r * 32 + (g ^ ((r >> 1) & 3)) * 8);
    }
#pragma unroll
    for (int i = 0; i < 2; ++i) {
      int r = wn * 32 + i * 16 + lr;
      bfr[i] = *(const bf16x8*)(Bt[cur] + r * 32 + (g ^ ((r >> 1) & 3)) * 8);
    }
#pragma unroll
    for (int mi = 0; mi < 4; ++mi)
#pragma unroll
      for (int ni = 0; ni < 2; ++ni)
        acc[mi][ni] = __builtin_amdgcn_mfma_f32_16x16x32_bf16(af[mi], bfr[ni],
                                                              acc[mi][ni], 0, 0, 0);
    __syncthreads();
  }
#undef GSTAGE

#pragma unroll
  for (int mi = 0; mi < 4; ++mi)
#pragma unroll
    for (int ni = 0; ni < 2; ++ni)
#pragma unroll
      for (int r = 0; r < 4; ++r) {
        int m = tileM + wm * 64 + mi * 16 + g * 4 + r;
        int n = tileN + wn * 32 + ni * 16 + lr;
        out[(size_t)m * N + n] = acc[mi][ni][r] + bias[n];
      }
}

// ---------------- flash attention v7: V staged in LDS ----------------
// v5 base + V tile in LDS (shared by 4 waves). Round-10 analysis: per-wave V
// register loads were 4x-redundant (vf independent of wv) = 32 KB/block/iter
// of L2 traffic vs 8 KB needed -> dominant per-iter cost. V^T tile (64 rows x
// 64 u16) is structurally identical to the K tile: same gload_lds staging,
// same XOR swizzle, same b128 read pattern (row&7 == lr&7 in both).
// LDS 50 KB/block -> still 2 blocks/CU. One barrier/iter covers K+V staging.
__global__ __launch_bounds__(256, 2) void attn_kernel(
    const u16* __restrict__ Qh, const u16* __restrict__ Kh,
    const u16* __restrict__ Vt, u16* __restrict__ Oout) {
  __shared__ __align__(16) u16 Kt[2][64 * 64];     // [buf] 8KB each
  __shared__ __align__(16) u16 Vl[2][64 * 64];     // [buf] 8KB each
  __shared__ __align__(16) u16 Plds[4][32 * 72];   // per-wave P staging
  const int lane = threadIdx.x & 63;
  const int wv   = threadIdx.x >> 6;
  const int lr = lane & 15, g = lane >> 4, lk = g * 8;
  const int swzm = (lr & 3) << 4;                  // P-staging col XOR mask
  const int sw = (blockIdx.x & 7) * 64 + (blockIdx.x >> 3);
  const int bh = sw >> 4;                          // 0..31
  const int qb = (sw & 15) * 128;
  const int b = bh >> 4, h = bh & 15;
  const size_t base = (size_t)bh * S_ * DK_;
  const int qrow = qb + wv * 32;
  u16* Pw = &Plds[wv][0];

  bf16x8 qf[2][2];
#pragma unroll
  for (int m = 0; m < 2; ++m)
#pragma unroll
    for (int i = 0; i < 2; ++i)
      qf[m][i] = *(const bf16x8*)(Qh + base + (size_t)(qrow + m * 16 + lr) * DK_ + i * 32 + lk);

  f32x4 acc[2][4];
  f32x4 lsum[2];
#pragma unroll
  for (int m = 0; m < 2; ++m) {
    lsum[m] = (f32x4){0.f, 0.f, 0.f, 0.f};
#pragma unroll
    for (int n = 0; n < 4; ++n) acc[m][n] = (f32x4){0.f, 0.f, 0.f, 0.f};
  }

  const float C1 = 0.18033688f;   // (1/sqrt(64)) * log2(e)
  const float C2 = 11.54156036f;  // 8 * log2(e)  (fixed shift; scores bounded)

  // Stage K tile (64 keys x 64 u16) + V^T tile (64 d x 64 u16), 4 chunks/thread.
#define STAGE_KV(nb, kbn) do {                                                 \
    _Pragma("unroll")                                                          \
    for (int r2 = 0; r2 < 2; ++r2) {                                           \
      int c = r2 * 256 + wv * 64 + lane;                                       \
      int row = c >> 3;                                                        \
      int scol = (((c & 7) * 16) ^ ((row & 7) << 4)) >> 1;                     \
      gload_lds16(Kh + base + (size_t)((kbn) + row) * DK_ + scol,              \
                  (void*)(Kt[nb] + (r2 * 256 + wv * 64) * 8));                 \
      gload_lds16(Vt + ((size_t)bh * DK_ + row) * S_ + (kbn) + scol,           \
                  (void*)(Vl[nb] + (r2 * 256 + wv * 64) * 8));                 \
    }                                                                          \
  } while (0)

  STAGE_KV(0, 0);
  __syncthreads();

  for (int kb = 0; kb < S_; kb += 64) {
    const int cur = (kb >> 6) & 1;
    if (kb + 64 < S_) STAGE_KV(cur ^ 1, kb + 64);
    // ---- K fragments from LDS (swizzled, 2-way conflict = free) ----
    bf16x8 kf[4][2];
#pragma unroll
    for (int f = 0; f < 4; ++f)
#pragma unroll
      for (int half = 0; half < 2; ++half) {
        const int swk = ((half * 64 + g * 16) ^ ((lr & 7) << 4)) >> 1;
        kf[f][half] = *(const bf16x8*)(Kt[cur] + (f * 16 + lr) * 64 + swk);
      }
    // ---- QK^T swapped: sc[f][m] rows=keys f*16+g*4+r, col=q m*16+lr ----
    f32x4 sc[4][2];
#pragma unroll
    for (int f = 0; f < 4; ++f) {
      sc[f][0] = (f32x4){0.f, 0.f, 0.f, 0.f};
      sc[f][1] = (f32x4){0.f, 0.f, 0.f, 0.f};
    }
#pragma unroll
    for (int f = 0; f < 4; ++f) {
      sc[f][0] = __builtin_amdgcn_mfma_f32_16x16x32_bf16(kf[f][0], qf[0][0], sc[f][0], 0, 0, 0);
      sc[f][0] = __builtin_amdgcn_mfma_f32_16x16x32_bf16(kf[f][1], qf[0][1], sc[f][0], 0, 0, 0);
      sc[f][1] = __builtin_amdgcn_mfma_f32_16x16x32_bf16(kf[f][0], qf[1][0], sc[f][1], 0, 0, 0);
      sc[f][1] = __builtin_amdgcn_mfma_f32_16x16x32_bf16(kf[f][1], qf[1][1], sc[f][1], 0, 0, 0);
    }
    // ---- fixed-shift softmax + pack + LDS write (keys r-contiguous) ----
#pragma unroll
    for (int m = 0; m < 2; ++m) {
      const int row = m * 16 + lr;
#pragma unroll
      for (int f = 0; f < 4; ++f) {
        f32x4 p;
        p[0] = __builtin_amdgcn_exp2f(fmaf(sc[f][m][0], C1, -C2));
        p[1] = __builtin_amdgcn_exp2f(fmaf(sc[f][m][1], C1, -C2));
        p[2] = __builtin_amdgcn_exp2f(fmaf(sc[f][m][2], C1, -C2));
        p[3] = __builtin_amdgcn_exp2f(fmaf(sc[f][m][3], C1, -C2));
        lsum[m] += p;
        uint2 w;
        w.x = cvt_pk_bf16(p[0], p[1]);
        w.y = cvt_pk_bf16(p[2], p[3]);
        *(uint2*)(Pw + row * 72 + ((f * 16 + g * 4) ^ swzm)) = w;
      }
    }
    // ---- PV: O[q][d] += P * V.  A=P from LDS, B=V from LDS ----
    bf16x8 pa[2][2];
#pragma unroll
    for (int m = 0; m < 2; ++m)
#pragma unroll
      for (int ks = 0; ks < 2; ++ks)
        pa[m][ks] = *(const bf16x8*)(Pw + (m * 16 + lr) * 72 + ((ks * 32 + lk) ^ swzm));
#pragma unroll
    for (int ks = 0; ks < 2; ++ks)
#pragma unroll
      for (int n = 0; n < 4; ++n) {
        const int swv = ((ks * 64 + g * 16) ^ ((lr & 7) << 4)) >> 1;
        bf16x8 vf = *(const bf16x8*)(Vl[cur] + (n * 16 + lr) * 64 + swv);
        acc[0][n] = __builtin_amdgcn_mfma_f32_16x16x32_bf16(pa[0][ks], vf, acc[0][n], 0, 0, 0);
        acc[1][n] = __builtin_amdgcn_mfma_f32_16x16x32_bf16(pa[1][ks], vf, acc[1][n], 0, 0, 0);
      }
    __syncthreads();   // drains K+V staging; all waves done reading cur
  }
#undef STAGE_KV

#pragma unroll
  for (int m = 0; m < 2; ++m) {
    float s = lsum[m][0] + lsum[m][1] + lsum[m][2] + lsum[m][3];
    s += __shfl_xor(s, 16);
    s += __shfl_xor(s, 32);
#pragma unroll
    for (int r = 0; r < 4; ++r) {
      float inv = 1.0f / __shfl(s, g * 4 + r);
      int row = b * S_ + qrow + m * 16 + g * 4 + r;
#pragma unroll
      for (int n = 0; n < 4; ++n)
        Oout[(size_t)row * D_ + h * 64 + n * 16 + lr] = f2bf(acc[m][n][r] * inv);
    }
  }
}

extern "C" void kernel_launch(void* const* d_in, const int* in_sizes, int n_in,
                              void* d_out, int out_size, void* d_ws, size_t ws_size,
                              hipStream_t stream) {
  const float* q    = (const float*)d_in[0];
  const float* k    = (const float*)d_in[1];
  const float* v    = (const float*)d_in[2];
  const float* Wq_w = (const float*)d_in[3];
  const float* Wq_b = (const float*)d_in[4];
  const float* Wk_w = (const float*)d_in[5];
  const float* Wk_b = (const float*)d_in[6];
  const float* Wv_w = (const float*)d_in[7];
  const float* Wv_b = (const float*)d_in[8];
  const float* Wo_w = (const float*)d_in[9];
  const float* Wo_b = (const float*)d_in[10];

  // -------- workspace layout: 40 MB, plus d_out (16.78 MB) as mid-stream
  // scratch for Kh/Vt (dead until final GEMM overwrites it).
  char* ws = (char*)d_ws;
  const size_t MB = 1024 * 1024;
  u16* Qh  = (u16*)(ws);                 //  [0,8)   QKV out: Q heads
  u16* qr  = (u16*)(ws + 8 * MB);        //  [8,16)  roped q  (concat A base)
  u16* kr  = (u16*)(ws + 16 * MB);       //  [16,24) roped k
  u16* vb  = (u16*)(ws + 24 * MB);       //  [24,32) bf16 v
  u16* Wqh = (u16*)(ws + 32 * MB);       //  [32,40) 4 weights (cvt4 contiguous)
  u16* Woh = (u16*)(ws + 38 * MB);
  u16* attn_o = (u16*)(ws + 8 * MB);     //  over qr (dead after QKV GEMM)
  u16* Kh  = (u16*)d_out;                //  d_out[0, 8.39MB)   K heads
  u16* Vt  = Kh + (size_t)B_ * H_ * S_ * DK_;  // d_out[8.39, 16.78MB) V^T

  rope_apply<<<dim3(B_ * S_), dim3(256), 0, stream>>>(q, k, v, qr, kr, vb);
  cvt4_k<<<dim3(4 * D_ * D_ / 4 / 256), dim3(256), 0, stream>>>(Wq_w, Wk_w, Wv_w, Wo_w, Wqh);

  gemm_qkv<<<dim3(96 * 16), dim3(256), 0, stream>>>(qr, Wqh, Wq_b, Wk_b, Wv_b,
                                                    Qh, Kh, Vt);

  attn_kernel<<<dim3(B_ * H_ * (S_ / 128)), dim3(256), 0, stream>>>(Qh, Kh, Vt, attn_o);

  const int M = B_ * S_, N = D_, K = D_;
  gemm_out<<<dim3((M / 128) * (N / 64)), dim3(256), 0, stream>>>(
      attn_o, Woh, Wo_b, (float*)d_out, M, N, K);
}